// Round 6
// baseline (34.475 us; speedup 1.0000x reference)
//
#include <hip/hip_runtime.h>
#include <hip/hip_bf16.h>

// Decompose: algebraically a single 5x5 conv with scalar taps
//   a_k = wS_k . wE_k  (k = i*5+j), bias = sum_k (wS_k . bE_k + bS_k)
//   out = clip( (sum_k a_k * xp[h+i, w+j] + bias) / 25, 0, 1 )
// over xp = reflect-pad(clip(x,0,1), 2). Shapes: x (4,3,1024,1024) fp32.
//
// R6: (a) lane-parallel prep: lane k*4+s computes a 16-elem slice of the
// k-th dot product (coalesced: lane l reads bytes [64l,64l+64)), 2x
// shfl_xor in 4-lane groups, 25 readlanes -> SGPRs. Chain ~300cyc vs R5's
// 25 serial 6-deep bpermute chains (~8us profiled).
// (b) TBH 8->4: grid 3072 (12 blocks/CU), acc[4][4], fewer VGPRs -> 32
// waves/CU to hide load latency (R5 was latency-bound: 17% HBM, 27% VALU).

#define HH 1024
#define WW 1024
#define NIMG 12
#define TBH 4              // output rows per thread/block-row
#define ROWS (TBH + 4)     // 8 input rows touched

typedef float f32x4 __attribute__((ext_vector_type(4)));

__device__ __forceinline__ float clip01(float v) {
    return fminf(fmaxf(v, 0.f), 1.f);
}

__device__ __forceinline__ float readlane_f(float v, int lane) {
    return __int_as_float(__builtin_amdgcn_readlane(__float_as_int(v), lane));
}

__device__ __forceinline__ float sgpr_bcast(float v) {
    return __int_as_float(__builtin_amdgcn_readfirstlane(__float_as_int(v)));
}

__device__ __forceinline__ float dot4(f32x4 a, f32x4 b) {
    return a.x * b.x + a.y * b.y + a.z * b.z + a.w * b.w;
}

__global__ __launch_bounds__(256) void conv5_kernel(const float* __restrict__ x,
                                                    const float* __restrict__ wE,
                                                    const float* __restrict__ bE,
                                                    const float* __restrict__ wS,
                                                    const float* __restrict__ bS,
                                                    float* __restrict__ out) {
    int lane = threadIdx.x & 63;

    // ---- Lane-parallel constant prep (per wave, redundant) ----
    // pass p in {0,1}: k = p*16 + (lane>>2), d-slice = (lane&3)*16 .. +15.
    float apass[2], cacc = 0.f;
    #pragma unroll
    for (int p = 0; p < 2; ++p) {
        int k = p * 16 + (lane >> 2);
        float a = 0.f;
        if (k < 25) {
            int base = k * 64 + (lane & 3) * 16;
            #pragma unroll
            for (int i = 0; i < 4; ++i) {
                f32x4 sv = *(const f32x4*)(wS + base + 4 * i);
                f32x4 ev = *(const f32x4*)(wE + base + 4 * i);
                f32x4 bv = *(const f32x4*)(bE + base + 4 * i);
                a += dot4(sv, ev);
                cacc += dot4(sv, bv);
            }
        }
        a += __shfl_xor(a, 1);
        a += __shfl_xor(a, 2);     // all 4 lanes of the group hold a_k
        apass[p] = a;
    }
    if (lane < 25) cacc += bS[lane];
    #pragma unroll
    for (int off = 32; off; off >>= 1) cacc += __shfl_xor(cacc, off);
    float bias = sgpr_bcast(cacc * (1.f / 25.f));

    float wv[25];
    #pragma unroll
    for (int k = 0; k < 16; ++k) wv[k] = readlane_f(apass[0], 4 * k) * (1.f / 25.f);
    #pragma unroll
    for (int k = 16; k < 25; ++k) wv[k] = readlane_f(apass[1], 4 * (k - 16)) * (1.f / 25.f);

    // ---- Tile mapping: XCD-aware bijective swizzle (3072 % 8 == 0) ----
    int nwg = gridDim.x;
    int cpx = nwg >> 3;
    int l = (blockIdx.x & 7) * cpx + (blockIdx.x >> 3);
    int img = l >> 8;                         // 256 row-blocks per image
    int rb = l & 255;
    int row0 = rb * TBH;

    const float* src = x + (size_t)img * (HH * WW);
    int tid = threadIdx.x;
    int cbase = tid * 4;                      // output col base

    // Column window: source cols cbase-2 .. cbase+5 (reflect at edges).
    bool lt = (cbase == 0);
    bool rt = (cbase == 1020);
    int qa = lt ? 0 : cbase - 2;
    int qb = rt ? 1020 : cbase + 2;

    float acc[TBH][4];
    #pragma unroll
    for (int r = 0; r < TBH; ++r)
        #pragma unroll
        for (int c = 0; c < 4; ++c) acc[r][c] = 0.f;

    #pragma unroll
    for (int ir = 0; ir < ROWS; ++ir) {
        int prow = row0 - 2 + ir;
        int sr = prow < 0 ? -prow : (prow >= HH ? 2 * HH - 2 - prow : prow);
        const float* rp = src + (size_t)sr * WW;
        f32x4 A = *(const f32x4*)(rp + qa);
        f32x4 B = *(const f32x4*)(rp + qb);

        float r8[8];
        if (lt) {
            r8[0]=A.z; r8[1]=A.y; r8[2]=A.x; r8[3]=A.y;
            r8[4]=B.x; r8[5]=B.y; r8[6]=B.z; r8[7]=B.w;
        } else if (rt) {
            r8[0]=A.x; r8[1]=A.y; r8[2]=A.z; r8[3]=A.w;
            r8[4]=B.z; r8[5]=B.w; r8[6]=B.z; r8[7]=B.y;
        } else {
            r8[0]=A.x; r8[1]=A.y; r8[2]=A.z; r8[3]=A.w;
            r8[4]=B.x; r8[5]=B.y; r8[6]=B.z; r8[7]=B.w;
        }
        #pragma unroll
        for (int j = 0; j < 8; ++j) r8[j] = clip01(r8[j]);

        #pragma unroll
        for (int dr = 0; dr < 5; ++dr) {
            int orow = ir - dr;
            if (orow < 0 || orow >= TBH) continue;
            #pragma unroll
            for (int j = 0; j < 5; ++j) {
                float wj = wv[dr * 5 + j];
                #pragma unroll
                for (int c = 0; c < 4; ++c)
                    acc[orow][c] = fmaf(wj, r8[c + j], acc[orow][c]);
            }
        }
    }

    // Epilogue: bias, clip, nontemporal coalesced 16B stores.
    float* op = out + (size_t)img * (HH * WW) + (size_t)row0 * WW + cbase;
    #pragma unroll
    for (int orow = 0; orow < TBH; ++orow) {
        f32x4 o;
        o.x = clip01(acc[orow][0] + bias);
        o.y = clip01(acc[orow][1] + bias);
        o.z = clip01(acc[orow][2] + bias);
        o.w = clip01(acc[orow][3] + bias);
        __builtin_nontemporal_store(o, (f32x4*)(op + (size_t)orow * WW));
    }
}

extern "C" void kernel_launch(void* const* d_in, const int* in_sizes, int n_in,
                              void* d_out, int out_size, void* d_ws, size_t ws_size,
                              hipStream_t stream) {
    const float* x  = (const float*)d_in[0];
    const float* wE = (const float*)d_in[1];
    const float* bE = (const float*)d_in[2];
    const float* wS = (const float*)d_in[3];
    const float* bS = (const float*)d_in[4];
    float* out = (float*)d_out;

    int nblocks = NIMG * (HH / TBH);   // 12 * 256 = 3072
    conv5_kernel<<<nblocks, 256, 0, stream>>>(x, wE, bE, wS, bS, out);
}

// Round 7
// 28.088 us; speedup vs baseline: 1.2274x; 1.2274x over previous
//
#include <hip/hip_runtime.h>
#include <hip/hip_bf16.h>

// Decompose: algebraically a single 5x5 conv with scalar taps
//   a_k = wS_k . wE_k  (k = i*5+j), bias = sum_k (wS_k . bE_k + bS_k)
//   out = clip( (sum_k a_k * xp[h+i, w+j] + bias) / 25, 0, 1 )
// over xp = reflect-pad(clip(x,0,1), 2). Shapes: x (4,3,1024,1024) fp32.
//
// R7: TBH back to 8 (R6's TBH=4 regressed). Explicit software pipeline:
// rotating 4-row register buffer; prologue issues rows 0..3, each iter
// consumes row ir and issues row ir+4. Fully unrolled -> static indices.
// Addresses R3/R5/R6 diagnosis: latency-bound from serialized load->use
// (VALU ~33%, HBM ~19%, occ ~40%), compiler wasn't hoisting loads.

#define HH 1024
#define WW 1024
#define NIMG 12
#define TBH 8              // output rows per thread/block-row
#define ROWS (TBH + 4)     // 12 input rows touched
#define PF 4               // prefetch depth (rows)

typedef float f32x4 __attribute__((ext_vector_type(4)));

__device__ __forceinline__ float clip01(float v) {
    return fminf(fmaxf(v, 0.f), 1.f);
}

__device__ __forceinline__ float readlane_f(float v, int lane) {
    return __int_as_float(__builtin_amdgcn_readlane(__float_as_int(v), lane));
}

__device__ __forceinline__ float sgpr_bcast(float v) {
    return __int_as_float(__builtin_amdgcn_readfirstlane(__float_as_int(v)));
}

__device__ __forceinline__ float dot4(f32x4 a, f32x4 b) {
    return a.x * b.x + a.y * b.y + a.z * b.z + a.w * b.w;
}

__global__ __launch_bounds__(256) void conv5_kernel(const float* __restrict__ x,
                                                    const float* __restrict__ wE,
                                                    const float* __restrict__ bE,
                                                    const float* __restrict__ wS,
                                                    const float* __restrict__ bS,
                                                    float* __restrict__ out) {
    int lane = threadIdx.x & 63;

    // ---- Lane-parallel constant prep (per wave, redundant; ~300 cyc) ----
    float apass[2], cacc = 0.f;
    #pragma unroll
    for (int p = 0; p < 2; ++p) {
        int k = p * 16 + (lane >> 2);
        float a = 0.f;
        if (k < 25) {
            int base = k * 64 + (lane & 3) * 16;
            #pragma unroll
            for (int i = 0; i < 4; ++i) {
                f32x4 sv = *(const f32x4*)(wS + base + 4 * i);
                f32x4 ev = *(const f32x4*)(wE + base + 4 * i);
                f32x4 bv = *(const f32x4*)(bE + base + 4 * i);
                a += dot4(sv, ev);
                cacc += dot4(sv, bv);
            }
        }
        a += __shfl_xor(a, 1);
        a += __shfl_xor(a, 2);     // all 4 lanes of the group hold a_k
        apass[p] = a;
    }
    if (lane < 25) cacc += bS[lane];
    #pragma unroll
    for (int off = 32; off; off >>= 1) cacc += __shfl_xor(cacc, off);
    float bias = sgpr_bcast(cacc * (1.f / 25.f));

    float wv[25];
    #pragma unroll
    for (int k = 0; k < 16; ++k) wv[k] = readlane_f(apass[0], 4 * k) * (1.f / 25.f);
    #pragma unroll
    for (int k = 16; k < 25; ++k) wv[k] = readlane_f(apass[1], 4 * (k - 16)) * (1.f / 25.f);

    // ---- Tile mapping: XCD-aware bijective swizzle (1536 % 8 == 0) ----
    int nwg = gridDim.x;
    int cpx = nwg >> 3;
    int l = (blockIdx.x & 7) * cpx + (blockIdx.x >> 3);
    int img = l >> 7;                         // 128 row-blocks per image
    int rb = l & 127;
    int row0 = rb * TBH;

    const float* src = x + (size_t)img * (HH * WW);
    int tid = threadIdx.x;
    int cbase = tid * 4;                      // output col base

    // Column window: source cols cbase-2 .. cbase+5 (reflect at edges).
    bool lt = (cbase == 0);
    bool rt = (cbase == 1020);
    int qa = lt ? 0 : cbase - 2;
    int qb = rt ? 1020 : cbase + 2;

    // Row pointer with vertical reflection (block-uniform scalar math).
    auto rowptr = [&](int ir) -> const float* {
        int prow = row0 - 2 + ir;
        int sr = prow < 0 ? -prow : (prow >= HH ? 2 * HH - 2 - prow : prow);
        return src + (size_t)sr * WW;
    };

    float acc[TBH][4];
    #pragma unroll
    for (int r = 0; r < TBH; ++r)
        #pragma unroll
        for (int c = 0; c < 4; ++c) acc[r][c] = 0.f;

    // ---- Software-pipelined main loop: rotating 4-row buffer ----
    f32x4 bufA[PF], bufB[PF];
    #pragma unroll
    for (int ir = 0; ir < PF; ++ir) {
        const float* rp = rowptr(ir);
        bufA[ir] = *(const f32x4*)(rp + qa);
        bufB[ir] = *(const f32x4*)(rp + qb);
    }

    #pragma unroll
    for (int ir = 0; ir < ROWS; ++ir) {
        f32x4 A = bufA[ir & (PF - 1)];
        f32x4 B = bufB[ir & (PF - 1)];
        if (ir + PF < ROWS) {
            const float* rp = rowptr(ir + PF);
            bufA[ir & (PF - 1)] = *(const f32x4*)(rp + qa);
            bufB[ir & (PF - 1)] = *(const f32x4*)(rp + qb);
        }

        float r8[8];
        if (lt) {
            r8[0]=A.z; r8[1]=A.y; r8[2]=A.x; r8[3]=A.y;
            r8[4]=B.x; r8[5]=B.y; r8[6]=B.z; r8[7]=B.w;
        } else if (rt) {
            r8[0]=A.x; r8[1]=A.y; r8[2]=A.z; r8[3]=A.w;
            r8[4]=B.z; r8[5]=B.w; r8[6]=B.z; r8[7]=B.y;
        } else {
            r8[0]=A.x; r8[1]=A.y; r8[2]=A.z; r8[3]=A.w;
            r8[4]=B.x; r8[5]=B.y; r8[6]=B.z; r8[7]=B.w;
        }
        #pragma unroll
        for (int j = 0; j < 8; ++j) r8[j] = clip01(r8[j]);

        #pragma unroll
        for (int dr = 0; dr < 5; ++dr) {
            int orow = ir - dr;
            if (orow < 0 || orow >= TBH) continue;
            #pragma unroll
            for (int j = 0; j < 5; ++j) {
                float wj = wv[dr * 5 + j];
                #pragma unroll
                for (int c = 0; c < 4; ++c)
                    acc[orow][c] = fmaf(wj, r8[c + j], acc[orow][c]);
            }
        }
    }

    // Epilogue: bias, clip, nontemporal coalesced 16B stores.
    float* op = out + (size_t)img * (HH * WW) + (size_t)row0 * WW + cbase;
    #pragma unroll
    for (int orow = 0; orow < TBH; ++orow) {
        f32x4 o;
        o.x = clip01(acc[orow][0] + bias);
        o.y = clip01(acc[orow][1] + bias);
        o.z = clip01(acc[orow][2] + bias);
        o.w = clip01(acc[orow][3] + bias);
        __builtin_nontemporal_store(o, (f32x4*)(op + (size_t)orow * WW));
    }
}

extern "C" void kernel_launch(void* const* d_in, const int* in_sizes, int n_in,
                              void* d_out, int out_size, void* d_ws, size_t ws_size,
                              hipStream_t stream) {
    const float* x  = (const float*)d_in[0];
    const float* wE = (const float*)d_in[1];
    const float* bE = (const float*)d_in[2];
    const float* wS = (const float*)d_in[3];
    const float* bS = (const float*)d_in[4];
    float* out = (float*)d_out;

    int nblocks = NIMG * (HH / TBH);   // 12 * 128 = 1536
    conv5_kernel<<<nblocks, 256, 0, stream>>>(x, wE, bE, wS, bS, out);
}

// Round 8
// 27.535 us; speedup vs baseline: 1.2520x; 1.0201x over previous
//
#include <hip/hip_runtime.h>
#include <hip/hip_bf16.h>

// Decompose: algebraically a single 5x5 conv with scalar taps
//   a_k = wS_k . wE_k  (k = i*5+j), bias = sum_k (wS_k . bE_k + bS_k)
//   out = clip( (sum_k a_k * xp[h+i, w+j] + bias) / 25, 0, 1 )
// over xp = reflect-pad(clip(x,0,1), 2). Shapes: x (4,3,1024,1024) fp32.
//
// R8: full-tile prefetch. All 24 row loads issued up-front (independent,
// pinned by sched_barrier(0)), consumed in issue order -> descending
// vmcnt waits; critical path ~= 1x latency + 12x200cyc instead of 12
// partially-covered stalls (R7: depth-4 covered ~800cyc of ~2000cyc
// effective burst latency). Stores interleaved (acc[ir-4] final after
// iter ir) to smooth the store burst and release registers early.

#define HH 1024
#define WW 1024
#define NIMG 12
#define TBH 8              // output rows per thread/block-row
#define ROWS (TBH + 4)     // 12 input rows touched

typedef float f32x4 __attribute__((ext_vector_type(4)));

__device__ __forceinline__ float clip01(float v) {
    return fminf(fmaxf(v, 0.f), 1.f);
}

__device__ __forceinline__ float readlane_f(float v, int lane) {
    return __int_as_float(__builtin_amdgcn_readlane(__float_as_int(v), lane));
}

__device__ __forceinline__ float sgpr_bcast(float v) {
    return __int_as_float(__builtin_amdgcn_readfirstlane(__float_as_int(v)));
}

__device__ __forceinline__ float dot4(f32x4 a, f32x4 b) {
    return a.x * b.x + a.y * b.y + a.z * b.z + a.w * b.w;
}

__global__ __launch_bounds__(256) void conv5_kernel(const float* __restrict__ x,
                                                    const float* __restrict__ wE,
                                                    const float* __restrict__ bE,
                                                    const float* __restrict__ wS,
                                                    const float* __restrict__ bS,
                                                    float* __restrict__ out) {
    int lane = threadIdx.x & 63;

    // ---- Lane-parallel constant prep (per wave, redundant; ~300 cyc) ----
    float apass[2], cacc = 0.f;
    #pragma unroll
    for (int p = 0; p < 2; ++p) {
        int k = p * 16 + (lane >> 2);
        float a = 0.f;
        if (k < 25) {
            int base = k * 64 + (lane & 3) * 16;
            #pragma unroll
            for (int i = 0; i < 4; ++i) {
                f32x4 sv = *(const f32x4*)(wS + base + 4 * i);
                f32x4 ev = *(const f32x4*)(wE + base + 4 * i);
                f32x4 bv = *(const f32x4*)(bE + base + 4 * i);
                a += dot4(sv, ev);
                cacc += dot4(sv, bv);
            }
        }
        a += __shfl_xor(a, 1);
        a += __shfl_xor(a, 2);     // all 4 lanes of the group hold a_k
        apass[p] = a;
    }
    if (lane < 25) cacc += bS[lane];
    #pragma unroll
    for (int off = 32; off; off >>= 1) cacc += __shfl_xor(cacc, off);
    float bias = sgpr_bcast(cacc * (1.f / 25.f));

    float wv[25];
    #pragma unroll
    for (int k = 0; k < 16; ++k) wv[k] = readlane_f(apass[0], 4 * k) * (1.f / 25.f);
    #pragma unroll
    for (int k = 16; k < 25; ++k) wv[k] = readlane_f(apass[1], 4 * (k - 16)) * (1.f / 25.f);

    // ---- Tile mapping: XCD-aware bijective swizzle (1536 % 8 == 0) ----
    int nwg = gridDim.x;
    int cpx = nwg >> 3;
    int l = (blockIdx.x & 7) * cpx + (blockIdx.x >> 3);
    int img = l >> 7;                         // 128 row-blocks per image
    int rb = l & 127;
    int row0 = rb * TBH;

    const float* src = x + (size_t)img * (HH * WW);
    int tid = threadIdx.x;
    int cbase = tid * 4;                      // output col base

    // Column window: source cols cbase-2 .. cbase+5 (reflect at edges).
    bool lt = (cbase == 0);
    bool rt = (cbase == 1020);
    int qa = lt ? 0 : cbase - 2;
    int qb = rt ? 1020 : cbase + 2;

    // Row pointer with vertical reflection (block-uniform scalar math).
    auto rowptr = [&](int ir) -> const float* {
        int prow = row0 - 2 + ir;
        int sr = prow < 0 ? -prow : (prow >= HH ? 2 * HH - 2 - prow : prow);
        return src + (size_t)sr * WW;
    };

    // ---- Issue ALL tile loads up-front (24 independent dwordx4) ----
    f32x4 bufA[ROWS], bufB[ROWS];
    #pragma unroll
    for (int ir = 0; ir < ROWS; ++ir) {
        const float* rp = rowptr(ir);
        bufA[ir] = *(const f32x4*)(rp + qa);
        bufB[ir] = *(const f32x4*)(rp + qb);
    }
    __builtin_amdgcn_sched_barrier(0);   // keep loads hoisted above compute

    float acc[TBH][4];
    #pragma unroll
    for (int r = 0; r < TBH; ++r)
        #pragma unroll
        for (int c = 0; c < 4; ++c) acc[r][c] = 0.f;

    float* op = out + (size_t)img * (HH * WW) + (size_t)row0 * WW + cbase;

    #pragma unroll
    for (int ir = 0; ir < ROWS; ++ir) {
        f32x4 A = bufA[ir];
        f32x4 B = bufB[ir];

        float r8[8];
        if (lt) {
            r8[0]=A.z; r8[1]=A.y; r8[2]=A.x; r8[3]=A.y;
            r8[4]=B.x; r8[5]=B.y; r8[6]=B.z; r8[7]=B.w;
        } else if (rt) {
            r8[0]=A.x; r8[1]=A.y; r8[2]=A.z; r8[3]=A.w;
            r8[4]=B.z; r8[5]=B.w; r8[6]=B.z; r8[7]=B.y;
        } else {
            r8[0]=A.x; r8[1]=A.y; r8[2]=A.z; r8[3]=A.w;
            r8[4]=B.x; r8[5]=B.y; r8[6]=B.z; r8[7]=B.w;
        }
        #pragma unroll
        for (int j = 0; j < 8; ++j) r8[j] = clip01(r8[j]);

        #pragma unroll
        for (int dr = 0; dr < 5; ++dr) {
            int orow = ir - dr;
            if (orow < 0 || orow >= TBH) continue;
            #pragma unroll
            for (int j = 0; j < 5; ++j) {
                float wj = wv[dr * 5 + j];
                #pragma unroll
                for (int c = 0; c < 4; ++c)
                    acc[orow][c] = fmaf(wj, r8[c + j], acc[orow][c]);
            }
        }

        // acc[ir-4] is final after this iteration: store it now.
        if (ir >= 4) {
            int orow = ir - 4;
            f32x4 o;
            o.x = clip01(acc[orow][0] + bias);
            o.y = clip01(acc[orow][1] + bias);
            o.z = clip01(acc[orow][2] + bias);
            o.w = clip01(acc[orow][3] + bias);
            __builtin_nontemporal_store(o, (f32x4*)(op + (size_t)orow * WW));
        }
    }
}

extern "C" void kernel_launch(void* const* d_in, const int* in_sizes, int n_in,
                              void* d_out, int out_size, void* d_ws, size_t ws_size,
                              hipStream_t stream) {
    const float* x  = (const float*)d_in[0];
    const float* wE = (const float*)d_in[1];
    const float* bE = (const float*)d_in[2];
    const float* wS = (const float*)d_in[3];
    const float* bS = (const float*)d_in[4];
    float* out = (float*)d_out;

    int nblocks = NIMG * (HH / TBH);   // 12 * 128 = 1536
    conv5_kernel<<<nblocks, 256, 0, stream>>>(x, wE, bE, wS, bS, out);
}

// Round 9
// 24.690 us; speedup vs baseline: 1.3963x; 1.1153x over previous
//
#include <hip/hip_runtime.h>
#include <hip/hip_bf16.h>

// Decompose: algebraically a single 5x5 conv with scalar taps
//   a_k = wS_k . wE_k  (k = i*5+j), bias = sum_k (wS_k . bE_k + bS_k)
//   out = clip( (sum_k a_k * xp[h+i, w+j] + bias) / 25, 0, 1 )
// over xp = reflect-pad(clip(x,0,1), 2). Shapes: x (4,3,1024,1024) fp32.
//
// R9: tall tiles + rotating buffers. Key insight: output row r is live only
// while input rows r..r+4 are consumed -> acc is a rotating 5-row buffer
// (20 VGPR) independent of tile height. TBH=16 (grid 768 = 3 blocks/CU
// exact), rolling 8-row load pipeline: issue rows 0..7 up-front, steady
// state = consume 1 row + issue 1 row + store 1 finished row. Halves
// per-tile fixed costs (prep/setup/epilogue), vertical halo 1.5x -> 1.25x.

#define HH 1024
#define WW 1024
#define NIMG 12
#define TBH 16             // output rows per block
#define ROWS (TBH + 4)     // 20 input rows touched
#define PF 8               // rolling load-buffer depth (rows)

typedef float f32x4 __attribute__((ext_vector_type(4)));

__device__ __forceinline__ float clip01(float v) {
    return fminf(fmaxf(v, 0.f), 1.f);
}

__device__ __forceinline__ float readlane_f(float v, int lane) {
    return __int_as_float(__builtin_amdgcn_readlane(__float_as_int(v), lane));
}

__device__ __forceinline__ float sgpr_bcast(float v) {
    return __int_as_float(__builtin_amdgcn_readfirstlane(__float_as_int(v)));
}

__device__ __forceinline__ float dot4(f32x4 a, f32x4 b) {
    return a.x * b.x + a.y * b.y + a.z * b.z + a.w * b.w;
}

__global__ __launch_bounds__(256) void conv5_kernel(const float* __restrict__ x,
                                                    const float* __restrict__ wE,
                                                    const float* __restrict__ bE,
                                                    const float* __restrict__ wS,
                                                    const float* __restrict__ bS,
                                                    float* __restrict__ out) {
    int lane = threadIdx.x & 63;

    // ---- Lane-parallel constant prep (per wave, redundant; ~300 cyc) ----
    float apass[2], cacc = 0.f;
    #pragma unroll
    for (int p = 0; p < 2; ++p) {
        int k = p * 16 + (lane >> 2);
        float a = 0.f;
        if (k < 25) {
            int base = k * 64 + (lane & 3) * 16;
            #pragma unroll
            for (int i = 0; i < 4; ++i) {
                f32x4 sv = *(const f32x4*)(wS + base + 4 * i);
                f32x4 ev = *(const f32x4*)(wE + base + 4 * i);
                f32x4 bv = *(const f32x4*)(bE + base + 4 * i);
                a += dot4(sv, ev);
                cacc += dot4(sv, bv);
            }
        }
        a += __shfl_xor(a, 1);
        a += __shfl_xor(a, 2);     // all 4 lanes of the group hold a_k
        apass[p] = a;
    }
    if (lane < 25) cacc += bS[lane];
    #pragma unroll
    for (int off = 32; off; off >>= 1) cacc += __shfl_xor(cacc, off);
    float bias = sgpr_bcast(cacc * (1.f / 25.f));

    float wv[25];
    #pragma unroll
    for (int k = 0; k < 16; ++k) wv[k] = readlane_f(apass[0], 4 * k) * (1.f / 25.f);
    #pragma unroll
    for (int k = 16; k < 25; ++k) wv[k] = readlane_f(apass[1], 4 * (k - 16)) * (1.f / 25.f);

    // ---- Tile mapping: XCD-aware bijective swizzle (768 % 8 == 0) ----
    // XCD k owns a contiguous run of row-blocks -> vertical halo neighbors
    // hit the same L2.
    int nwg = gridDim.x;
    int cpx = nwg >> 3;
    int l = (blockIdx.x & 7) * cpx + (blockIdx.x >> 3);
    int img = l >> 6;                         // 64 row-blocks per image
    int rb = l & 63;
    int row0 = rb * TBH;

    const float* src = x + (size_t)img * (HH * WW);
    int tid = threadIdx.x;
    int cbase = tid * 4;                      // output col base

    // Column window: source cols cbase-2 .. cbase+5 (reflect at edges).
    bool lt = (cbase == 0);
    bool rt = (cbase == 1020);
    int qa = lt ? 0 : cbase - 2;
    int qb = rt ? 1020 : cbase + 2;

    // Row pointer with vertical reflection (block-uniform scalar math).
    auto rowptr = [&](int ir) -> const float* {
        int prow = row0 - 2 + ir;
        int sr = prow < 0 ? -prow : (prow >= HH ? 2 * HH - 2 - prow : prow);
        return src + (size_t)sr * WW;
    };

    // ---- Rolling structures ----
    f32x4 bufA[PF], bufB[PF];        // load pipeline, depth 8 rows
    float acc[5][4];                 // rotating output-row accumulators

    #pragma unroll
    for (int ir = 0; ir < PF; ++ir) {
        const float* rp = rowptr(ir);
        bufA[ir] = *(const f32x4*)(rp + qa);
        bufB[ir] = *(const f32x4*)(rp + qb);
    }
    __builtin_amdgcn_sched_barrier(0);   // keep prologue loads hoisted

    float* op = out + (size_t)img * (HH * WW) + (size_t)row0 * WW + cbase;

    #pragma unroll
    for (int ir = 0; ir < ROWS; ++ir) {
        f32x4 A = bufA[ir & (PF - 1)];
        f32x4 B = bufB[ir & (PF - 1)];
        if (ir + PF < ROWS) {
            const float* rp = rowptr(ir + PF);
            bufA[ir & (PF - 1)] = *(const f32x4*)(rp + qa);
            bufB[ir & (PF - 1)] = *(const f32x4*)(rp + qb);
        }

        float r8[8];
        if (lt) {
            r8[0]=A.z; r8[1]=A.y; r8[2]=A.x; r8[3]=A.y;
            r8[4]=B.x; r8[5]=B.y; r8[6]=B.z; r8[7]=B.w;
        } else if (rt) {
            r8[0]=A.x; r8[1]=A.y; r8[2]=A.z; r8[3]=A.w;
            r8[4]=B.z; r8[5]=B.w; r8[6]=B.z; r8[7]=B.y;
        } else {
            r8[0]=A.x; r8[1]=A.y; r8[2]=A.z; r8[3]=A.w;
            r8[4]=B.x; r8[5]=B.y; r8[6]=B.z; r8[7]=B.w;
        }
        #pragma unroll
        for (int j = 0; j < 8; ++j) r8[j] = clip01(r8[j]);

        // Output row ir starts here: zero its rotating slot.
        if (ir < TBH) {
            #pragma unroll
            for (int c = 0; c < 4; ++c) acc[ir % 5][c] = 0.f;
        }

        // Input row ir contributes to output rows ir-4 .. ir.
        #pragma unroll
        for (int dr = 0; dr < 5; ++dr) {
            int orow = ir - dr;
            if (orow < 0 || orow >= TBH) continue;
            #pragma unroll
            for (int j = 0; j < 5; ++j) {
                float wj = wv[dr * 5 + j];
                #pragma unroll
                for (int c = 0; c < 4; ++c)
                    acc[orow % 5][c] = fmaf(wj, r8[c + j], acc[orow % 5][c]);
            }
        }

        // Output row ir-4 is final: store and free its slot.
        if (ir >= 4) {
            int orow = ir - 4;
            f32x4 o;
            o.x = clip01(acc[orow % 5][0] + bias);
            o.y = clip01(acc[orow % 5][1] + bias);
            o.z = clip01(acc[orow % 5][2] + bias);
            o.w = clip01(acc[orow % 5][3] + bias);
            __builtin_nontemporal_store(o, (f32x4*)(op + (size_t)orow * WW));
        }
    }
}

extern "C" void kernel_launch(void* const* d_in, const int* in_sizes, int n_in,
                              void* d_out, int out_size, void* d_ws, size_t ws_size,
                              hipStream_t stream) {
    const float* x  = (const float*)d_in[0];
    const float* wE = (const float*)d_in[1];
    const float* bE = (const float*)d_in[2];
    const float* wS = (const float*)d_in[3];
    const float* bS = (const float*)d_in[4];
    float* out = (float*)d_out;

    int nblocks = NIMG * (HH / TBH);   // 12 * 64 = 768
    conv5_kernel<<<nblocks, 256, 0, stream>>>(x, wE, bE, wS, bS, out);
}

// Round 10
// 23.606 us; speedup vs baseline: 1.4604x; 1.0459x over previous
//
#include <hip/hip_runtime.h>
#include <hip/hip_bf16.h>

// Decompose: algebraically a single 5x5 conv with scalar taps
//   a_k = wS_k . wE_k  (k = i*5+j), bias = sum_k (wS_k . bE_k + bS_k)
//   out = clip( (sum_k a_k * xp[h+i, w+j] + bias) / 25, 0, 1 )
// over xp = reflect-pad(clip(x,0,1), 2). Shapes: x (4,3,1024,1024) fp32.
//
// R10 = R9 structure (TBH=16, rotating 5-row acc, PF=8 rolling loads,
// grid 768 = 3 blocks/CU) + PACKED fp32 math. gfx950's 157 TF fp32 is the
// v_pk_fma_f32 (VOP3P) rate; scalar v_fmac runs at half. Inner loop
// rewritten in f32x2 (clang contracts to pk_fma; elementwise_min/max ->
// pk_min/max): ~2200 -> ~1300 VALU insts/thread. Occupancy is grid-capped
// so the extra packing VGPRs are free.

#define HH 1024
#define WW 1024
#define NIMG 12
#define TBH 16             // output rows per block
#define ROWS (TBH + 4)     // 20 input rows touched
#define PF 8               // rolling load-buffer depth (rows)

typedef float f32x4 __attribute__((ext_vector_type(4)));
typedef float f32x2 __attribute__((ext_vector_type(2)));

__device__ __forceinline__ float readlane_f(float v, int lane) {
    return __int_as_float(__builtin_amdgcn_readlane(__float_as_int(v), lane));
}

__device__ __forceinline__ float sgpr_bcast(float v) {
    return __int_as_float(__builtin_amdgcn_readfirstlane(__float_as_int(v)));
}

__device__ __forceinline__ float dot4(f32x4 a, f32x4 b) {
    return a.x * b.x + a.y * b.y + a.z * b.z + a.w * b.w;
}

__device__ __forceinline__ f32x4 clip01v4(f32x4 v) {
    f32x4 z = {0.f, 0.f, 0.f, 0.f};
    f32x4 o = {1.f, 1.f, 1.f, 1.f};
    return __builtin_elementwise_min(__builtin_elementwise_max(v, z), o);
}

__device__ __forceinline__ f32x2 clip01v2(f32x2 v) {
    f32x2 z = {0.f, 0.f};
    f32x2 o = {1.f, 1.f};
    return __builtin_elementwise_min(__builtin_elementwise_max(v, z), o);
}

__global__ __launch_bounds__(256) void conv5_kernel(const float* __restrict__ x,
                                                    const float* __restrict__ wE,
                                                    const float* __restrict__ bE,
                                                    const float* __restrict__ wS,
                                                    const float* __restrict__ bS,
                                                    float* __restrict__ out) {
    int lane = threadIdx.x & 63;

    // ---- Lane-parallel constant prep (per wave, redundant; ~300 cyc) ----
    float apass[2], cacc = 0.f;
    #pragma unroll
    for (int p = 0; p < 2; ++p) {
        int k = p * 16 + (lane >> 2);
        float a = 0.f;
        if (k < 25) {
            int base = k * 64 + (lane & 3) * 16;
            #pragma unroll
            for (int i = 0; i < 4; ++i) {
                f32x4 sv = *(const f32x4*)(wS + base + 4 * i);
                f32x4 ev = *(const f32x4*)(wE + base + 4 * i);
                f32x4 bv = *(const f32x4*)(bE + base + 4 * i);
                a += dot4(sv, ev);
                cacc += dot4(sv, bv);
            }
        }
        a += __shfl_xor(a, 1);
        a += __shfl_xor(a, 2);     // all 4 lanes of the group hold a_k
        apass[p] = a;
    }
    if (lane < 25) cacc += bS[lane];
    #pragma unroll
    for (int off = 32; off; off >>= 1) cacc += __shfl_xor(cacc, off);
    float bias = sgpr_bcast(cacc * (1.f / 25.f));
    f32x2 bias2 = {bias, bias};

    float wv[25];
    #pragma unroll
    for (int k = 0; k < 16; ++k) wv[k] = readlane_f(apass[0], 4 * k) * (1.f / 25.f);
    #pragma unroll
    for (int k = 16; k < 25; ++k) wv[k] = readlane_f(apass[1], 4 * (k - 16)) * (1.f / 25.f);

    // ---- Tile mapping: XCD-aware bijective swizzle (768 % 8 == 0) ----
    int nwg = gridDim.x;
    int cpx = nwg >> 3;
    int l = (blockIdx.x & 7) * cpx + (blockIdx.x >> 3);
    int img = l >> 6;                         // 64 row-blocks per image
    int rb = l & 63;
    int row0 = rb * TBH;

    const float* src = x + (size_t)img * (HH * WW);
    int tid = threadIdx.x;
    int cbase = tid * 4;                      // output col base

    // Column window: source cols cbase-2 .. cbase+5 (reflect at edges).
    bool lt = (cbase == 0);
    bool rt = (cbase == 1020);
    int qa = lt ? 0 : cbase - 2;
    int qb = rt ? 1020 : cbase + 2;

    // Row pointer with vertical reflection (block-uniform scalar math).
    auto rowptr = [&](int ir) -> const float* {
        int prow = row0 - 2 + ir;
        int sr = prow < 0 ? -prow : (prow >= HH ? 2 * HH - 2 - prow : prow);
        return src + (size_t)sr * WW;
    };

    // ---- Rolling structures ----
    f32x4 bufA[PF], bufB[PF];        // load pipeline, depth 8 rows
    f32x2 acc[5][2];                 // rotating output-row accumulators (packed)

    #pragma unroll
    for (int ir = 0; ir < PF; ++ir) {
        const float* rp = rowptr(ir);
        bufA[ir] = *(const f32x4*)(rp + qa);
        bufB[ir] = *(const f32x4*)(rp + qb);
    }
    __builtin_amdgcn_sched_barrier(0);   // keep prologue loads hoisted

    float* op = out + (size_t)img * (HH * WW) + (size_t)row0 * WW + cbase;

    #pragma unroll
    for (int ir = 0; ir < ROWS; ++ir) {
        f32x4 A = bufA[ir & (PF - 1)];
        f32x4 B = bufB[ir & (PF - 1)];
        if (ir + PF < ROWS) {
            const float* rp = rowptr(ir + PF);
            bufA[ir & (PF - 1)] = *(const f32x4*)(rp + qa);
            bufB[ir & (PF - 1)] = *(const f32x4*)(rp + qb);
        }

        // Packed clip (selection below is a permutation of clipped values).
        A = clip01v4(A);
        B = clip01v4(B);

        float r8[8];
        if (lt) {
            r8[0]=A.z; r8[1]=A.y; r8[2]=A.x; r8[3]=A.y;
            r8[4]=B.x; r8[5]=B.y; r8[6]=B.z; r8[7]=B.w;
        } else if (rt) {
            r8[0]=A.x; r8[1]=A.y; r8[2]=A.z; r8[3]=A.w;
            r8[4]=B.z; r8[5]=B.w; r8[6]=B.z; r8[7]=B.y;
        } else {
            r8[0]=A.x; r8[1]=A.y; r8[2]=A.z; r8[3]=A.w;
            r8[4]=B.x; r8[5]=B.y; r8[6]=B.z; r8[7]=B.w;
        }

        // Sliding pairs: pr[j] = {r8[j], r8[j+1]}, j = 0..6.
        f32x2 pr[7];
        #pragma unroll
        for (int j = 0; j < 7; ++j) { pr[j].x = r8[j]; pr[j].y = r8[j + 1]; }

        // Output row ir starts here: zero its rotating slot.
        if (ir < TBH) {
            acc[ir % 5][0] = (f32x2){0.f, 0.f};
            acc[ir % 5][1] = (f32x2){0.f, 0.f};
        }

        // Input row ir contributes to output rows ir-4 .. ir (packed FMA).
        #pragma unroll
        for (int dr = 0; dr < 5; ++dr) {
            int orow = ir - dr;
            if (orow < 0 || orow >= TBH) continue;
            #pragma unroll
            for (int j = 0; j < 5; ++j) {
                float wj = wv[dr * 5 + j];
                f32x2 w2 = {wj, wj};
                acc[orow % 5][0] += pr[j] * w2;       // cols 0,1
                acc[orow % 5][1] += pr[j + 2] * w2;   // cols 2,3
            }
        }

        // Output row ir-4 is final: packed bias+clip, NT store.
        if (ir >= 4) {
            int orow = ir - 4;
            f32x2 lo = clip01v2(acc[orow % 5][0] + bias2);
            f32x2 hi = clip01v2(acc[orow % 5][1] + bias2);
            f32x4 o = {lo.x, lo.y, hi.x, hi.y};
            __builtin_nontemporal_store(o, (f32x4*)(op + (size_t)orow * WW));
        }
    }
}

extern "C" void kernel_launch(void* const* d_in, const int* in_sizes, int n_in,
                              void* d_out, int out_size, void* d_ws, size_t ws_size,
                              hipStream_t stream) {
    const float* x  = (const float*)d_in[0];
    const float* wE = (const float*)d_in[1];
    const float* bE = (const float*)d_in[2];
    const float* wS = (const float*)d_in[3];
    const float* bS = (const float*)d_in[4];
    float* out = (float*)d_out;

    int nblocks = NIMG * (HH / TBH);   // 12 * 64 = 768
    conv5_kernel<<<nblocks, 256, 0, stream>>>(x, wE, bE, wS, bS, out);
}